// Round 8
// baseline (100.748 us; speedup 1.0000x reference)
//
#include <hip/hip_runtime.h>
#include <cmath>

#define HID 1024
#define OUTN 512
#define VOCABN 1024
#define MSIZE 262144
#define MDIM 128

// workspace layout (floats)
#define WS_TIH 0      // [1024] W_ih@input + b_ih
#define WS_HB  1024   // [1024] hidden_bar
#define WS_H   2048   // [1024] h
#define WS_AW  3072   // [2]    softmax action weights
#define WS_NE  3076   // [128]  new_elt (16B aligned: 3076*4 % 16 == 0)

__device__ __forceinline__ float wred(float v) {
#pragma unroll
    for (int m = 32; m; m >>= 1) v += __shfl_xor(v, m, 64);
    return v;
}

// wave-cooperative dot over n4 float4s (all 64 lanes participate; result in all lanes)
__device__ __forceinline__ float dot4(const float4* __restrict__ a,
                                      const float4* __restrict__ b,
                                      int n4, int lane) {
    float acc = 0.f;
    for (int k = lane; k < n4; k += 64) {
        float4 x = a[k], y = b[k];
        acc = fmaf(x.x, y.x, acc);
        acc = fmaf(x.y, y.y, acc);
        acc = fmaf(x.z, y.z, acc);
        acc = fmaf(x.w, y.w, acc);
    }
    return wred(acc);
}

__device__ __forceinline__ float4 blend4(float aw0, float aw1, float4 push, float4 pop) {
    float4 r;
    r.x = fmaf(aw0, push.x, aw1 * pop.x);
    r.y = fmaf(aw0, push.y, aw1 * pop.y);
    r.z = fmaf(aw0, push.z, aw1 * pop.z);
    r.w = fmaf(aw0, push.w, aw1 * pop.w);
    return r;
}

// Kernel A: t_ih[row] = W_ih[row,:]·input + b_ih[row]
//           hidden_bar[row] = W_sh[row,:]·stack[0,:] + b_sh[row] + hidden0[row]
__global__ void k_pre(const float* __restrict__ input, const float* __restrict__ hidden0,
                      const float* __restrict__ stack, const float* __restrict__ W_ih,
                      const float* __restrict__ b_ih, const float* __restrict__ W_sh,
                      const float* __restrict__ b_sh, float* __restrict__ ws) {
    const int lane = threadIdx.x & 63;
    const int row = blockIdx.x * (blockDim.x >> 6) + (threadIdx.x >> 6);
    if (row >= HID) return;
    float t  = dot4((const float4*)(W_ih + row * VOCABN), (const float4*)input, VOCABN / 4, lane);
    float hb = dot4((const float4*)(W_sh + row * MDIM), (const float4*)stack, MDIM / 4, lane);
    if (lane == 0) {
        ws[WS_TIH + row] = t + b_ih[row];
        ws[WS_HB + row]  = hb + b_sh[row] + hidden0[row];
    }
}

// Kernel B: h[row] = tanh(t_ih[row] + W_hh[row,:]·hidden_bar + b_hh[row])
__global__ void k_h(const float* __restrict__ W_hh, const float* __restrict__ b_hh,
                    float* __restrict__ ws, float* __restrict__ d_out) {
    const int lane = threadIdx.x & 63;
    const int row = blockIdx.x * (blockDim.x >> 6) + (threadIdx.x >> 6);
    if (row >= HID) return;
    float a = dot4((const float4*)(W_hh + row * HID), (const float4*)(ws + WS_HB), HID / 4, lane);
    if (lane == 0) {
        float h = tanhf(ws[WS_TIH + row] + a + b_hh[row]);
        ws[WS_H + row] = h;
        d_out[OUTN + row] = h;  // h is output #1 (after 512 floats of `output`)
    }
}

// Kernel C: output (512), new_elt (128), action softmax (1 wave)
__global__ void k_heads(const float* __restrict__ W_y, const float* __restrict__ b_y,
                        const float* __restrict__ W_n, const float* __restrict__ b_n,
                        const float* __restrict__ W_a, const float* __restrict__ b_a,
                        float* __restrict__ ws, float* __restrict__ d_out) {
    const int lane = threadIdx.x & 63;
    const int row = blockIdx.x * (blockDim.x >> 6) + (threadIdx.x >> 6);
    const float4* h4 = (const float4*)(ws + WS_H);
    if (row < OUTN) {
        float a = dot4((const float4*)(W_y + row * HID), h4, HID / 4, lane);
        if (lane == 0) d_out[row] = 1.f / (1.f + expf(-(a + b_y[row])));
    } else if (row < OUTN + MDIM) {
        const int m = row - OUTN;
        float a = dot4((const float4*)(W_n + m * HID), h4, HID / 4, lane);
        if (lane == 0) ws[WS_NE + m] = 1.f / (1.f + expf(-(a + b_n[m])));
    } else if (row == OUTN + MDIM) {
        float l0 = dot4((const float4*)(W_a), h4, HID / 4, lane);
        float l1 = dot4((const float4*)(W_a + HID), h4, HID / 4, lane);
        if (lane == 0) {
            l0 += b_a[0];
            l1 += b_a[1];
            const float mx = fmaxf(l0, l1);
            const float e0 = expf(l0 - mx), e1 = expf(l1 - mx);
            const float s = e0 + e1;
            ws[WS_AW]     = e0 / s;
            ws[WS_AW + 1] = e1 / s;
        }
    }
}

// Kernel D: blend, 2 float4s (32B) per thread per iteration.
// Pair p covers float4s {2p, 2p+1}; both always within one stack row
// (row boundaries are at multiples of 32 float4s, 2p+1 is never one).
__global__ __launch_bounds__(256) void k_stack(
    const float* __restrict__ stack, const float* __restrict__ ws,
    float* __restrict__ out_stack) {
    const float aw0 = ws[WS_AW];
    const float aw1 = ws[WS_AW + 1];
    const float4* s4  = (const float4*)stack;
    const float4* ne4 = (const float4*)(ws + WS_NE);
    float4* o4 = (float4*)out_stack;
    const int total8 = MSIZE * (MDIM / 8);  // 4,194,304 pairs
    const int stride = gridDim.x * blockDim.x;
    const int gid = blockIdx.x * blockDim.x + threadIdx.x;
#pragma unroll 4
    for (int p = gid; p < total8; p += stride) {
        const int f = p * 2;
        const int row = f >> 5;
        float4 pu0, pu1, po0, po1;
        if (row == 0) {
            pu0 = ne4[f & 31];
            pu1 = ne4[(f & 31) + 1];
        } else {
            pu0 = s4[f - 32];
            pu1 = s4[f - 31];
        }
        if (row == MSIZE - 1) {
            po0 = make_float4(0.f, 0.f, 0.f, 0.f);
            po1 = po0;
        } else {
            po0 = s4[f + 32];
            po1 = s4[f + 33];
        }
        o4[f]     = blend4(aw0, aw1, pu0, po0);
        o4[f + 1] = blend4(aw0, aw1, pu1, po1);
    }
}

extern "C" void kernel_launch(void* const* d_in, const int* in_sizes, int n_in,
                              void* d_out, int out_size, void* d_ws, size_t ws_size,
                              hipStream_t stream) {
    const float* input   = (const float*)d_in[0];
    const float* hidden0 = (const float*)d_in[1];
    const float* stack   = (const float*)d_in[2];
    const float* W_ih    = (const float*)d_in[3];
    const float* W_hh    = (const float*)d_in[4];
    const float* b_ih    = (const float*)d_in[5];
    const float* b_hh    = (const float*)d_in[6];
    const float* W_y     = (const float*)d_in[7];
    const float* b_y     = (const float*)d_in[8];
    const float* W_n     = (const float*)d_in[9];
    const float* b_n     = (const float*)d_in[10];
    const float* W_a     = (const float*)d_in[11];
    const float* b_a     = (const float*)d_in[12];
    const float* W_sh    = (const float*)d_in[13];
    const float* b_sh    = (const float*)d_in[14];
    float* out = (float*)d_out;
    float* ws  = (float*)d_ws;

    // A: 1024 rows, 4 waves/block -> 256 blocks
    k_pre<<<256, 256, 0, stream>>>(input, hidden0, stack, W_ih, b_ih, W_sh, b_sh, ws);
    // B: 1024 rows
    k_h<<<256, 256, 0, stream>>>(W_hh, b_hh, ws, out);
    // C: 641 rows -> ceil(641/4) = 161 blocks
    k_heads<<<161, 256, 0, stream>>>(W_y, b_y, W_n, b_n, W_a, b_a, ws, out);
    // D: blend, 2 float4/thread, grid-stride
    k_stack<<<2048, 256, 0, stream>>>(stack, ws, out + OUTN + HID);
}

// Round 9
// 69.852 us; speedup vs baseline: 1.4423x; 1.4423x over previous
//
#include <hip/hip_runtime.h>
#include <cmath>

#define HID 1024
#define OUTN 512
#define VOCABN 1024
#define MSIZE 262144
#define MDIM 128

// workspace layout (floats)
#define WS_TIH 0      // [1024] W_ih@input + b_ih
#define WS_HB  1024   // [1024] hidden_bar
#define WS_H   2048   // [1024] h
#define WS_AW  3072   // [2]    softmax action weights
#define WS_NE  3076   // [128]  new_elt (16B aligned: 3076*4 % 16 == 0)

__device__ __forceinline__ float wred(float v) {
#pragma unroll
    for (int m = 32; m; m >>= 1) v += __shfl_xor(v, m, 64);
    return v;
}

// wave-cooperative dot over n4 float4s (all 64 lanes participate; result in all lanes)
__device__ __forceinline__ float dot4(const float4* __restrict__ a,
                                      const float4* __restrict__ b,
                                      int n4, int lane) {
    float acc = 0.f;
    for (int k = lane; k < n4; k += 64) {
        float4 x = a[k], y = b[k];
        acc = fmaf(x.x, y.x, acc);
        acc = fmaf(x.y, y.y, acc);
        acc = fmaf(x.z, y.z, acc);
        acc = fmaf(x.w, y.w, acc);
    }
    return wred(acc);
}

__device__ __forceinline__ float4 blend4(float aw0, float aw1, float4 push, float4 pop) {
    float4 r;
    r.x = fmaf(aw0, push.x, aw1 * pop.x);
    r.y = fmaf(aw0, push.y, aw1 * pop.y);
    r.z = fmaf(aw0, push.z, aw1 * pop.z);
    r.w = fmaf(aw0, push.w, aw1 * pop.w);
    return r;
}

// Kernel A: t_ih[row] = W_ih[row,:]·input + b_ih[row]
//           hidden_bar[row] = W_sh[row,:]·stack[0,:] + b_sh[row] + hidden0[row]
__global__ void k_pre(const float* __restrict__ input, const float* __restrict__ hidden0,
                      const float* __restrict__ stack, const float* __restrict__ W_ih,
                      const float* __restrict__ b_ih, const float* __restrict__ W_sh,
                      const float* __restrict__ b_sh, float* __restrict__ ws) {
    const int lane = threadIdx.x & 63;
    const int row = blockIdx.x * (blockDim.x >> 6) + (threadIdx.x >> 6);
    if (row >= HID) return;
    float t  = dot4((const float4*)(W_ih + row * VOCABN), (const float4*)input, VOCABN / 4, lane);
    float hb = dot4((const float4*)(W_sh + row * MDIM), (const float4*)stack, MDIM / 4, lane);
    if (lane == 0) {
        ws[WS_TIH + row] = t + b_ih[row];
        ws[WS_HB + row]  = hb + b_sh[row] + hidden0[row];
    }
}

// Kernel B: h[row] = tanh(t_ih[row] + W_hh[row,:]·hidden_bar + b_hh[row])
__global__ void k_h(const float* __restrict__ W_hh, const float* __restrict__ b_hh,
                    float* __restrict__ ws, float* __restrict__ d_out) {
    const int lane = threadIdx.x & 63;
    const int row = blockIdx.x * (blockDim.x >> 6) + (threadIdx.x >> 6);
    if (row >= HID) return;
    float a = dot4((const float4*)(W_hh + row * HID), (const float4*)(ws + WS_HB), HID / 4, lane);
    if (lane == 0) {
        float h = tanhf(ws[WS_TIH + row] + a + b_hh[row]);
        ws[WS_H + row] = h;
        d_out[OUTN + row] = h;  // h is output #1 (after 512 floats of `output`)
    }
}

// Kernel C: output (512), new_elt (128), action softmax (1 wave)
__global__ void k_heads(const float* __restrict__ W_y, const float* __restrict__ b_y,
                        const float* __restrict__ W_n, const float* __restrict__ b_n,
                        const float* __restrict__ W_a, const float* __restrict__ b_a,
                        float* __restrict__ ws, float* __restrict__ d_out) {
    const int lane = threadIdx.x & 63;
    const int row = blockIdx.x * (blockDim.x >> 6) + (threadIdx.x >> 6);
    const float4* h4 = (const float4*)(ws + WS_H);
    if (row < OUTN) {
        float a = dot4((const float4*)(W_y + row * HID), h4, HID / 4, lane);
        if (lane == 0) d_out[row] = 1.f / (1.f + expf(-(a + b_y[row])));
    } else if (row < OUTN + MDIM) {
        const int m = row - OUTN;
        float a = dot4((const float4*)(W_n + m * HID), h4, HID / 4, lane);
        if (lane == 0) ws[WS_NE + m] = 1.f / (1.f + expf(-(a + b_n[m])));
    } else if (row == OUTN + MDIM) {
        float l0 = dot4((const float4*)(W_a), h4, HID / 4, lane);
        float l1 = dot4((const float4*)(W_a + HID), h4, HID / 4, lane);
        if (lane == 0) {
            l0 += b_a[0];
            l1 += b_a[1];
            const float mx = fmaxf(l0, l1);
            const float e0 = expf(l0 - mx), e1 = expf(l1 - mx);
            const float s = e0 + e1;
            ws[WS_AW]     = e0 / s;
            ws[WS_AW + 1] = e1 / s;
        }
    }
}

// Kernel D: blend, grid-stride, 1 float4/thread/iter (R7 pattern), but
// BRANCHLESS body (pointer/value selects) + unroll so loads cluster across
// iterations, and explicit occupancy request (8 waves/SIMD).
__global__ __launch_bounds__(256, 8) void k_stack(
    const float* __restrict__ stack, const float* __restrict__ ws,
    float* __restrict__ out_stack) {
    const float aw0 = ws[WS_AW];
    const float aw1 = ws[WS_AW + 1];
    const float4* s4  = (const float4*)stack;
    const float4* ne4 = (const float4*)(ws + WS_NE);
    float4* o4 = (float4*)out_stack;
    const int total4 = MSIZE * (MDIM / 4);  // 8,388,608; 32 float4 per row
    const int stride = gridDim.x * blockDim.x;  // 524,288 -> exactly 16 iters
    const int gid = blockIdx.x * blockDim.x + threadIdx.x;
#pragma unroll 4
    for (int e = gid; e < total4; e += stride) {
        const int row = e >> 5;
        // push: row 0 takes new_elt (e&31 == e there); else stack row-1.
        const float4* pp = (row == 0) ? (ne4 + e) : (s4 + (e - 32));
        // pop: last row is zero; clamp address in-bounds, select value below.
        const int pe = (row == MSIZE - 1) ? (e - 32) : (e + 32);
        const float4 push = *pp;
        float4 pop = s4[pe];
        if (row == MSIZE - 1) pop = make_float4(0.f, 0.f, 0.f, 0.f);
        o4[e] = blend4(aw0, aw1, push, pop);
    }
}

extern "C" void kernel_launch(void* const* d_in, const int* in_sizes, int n_in,
                              void* d_out, int out_size, void* d_ws, size_t ws_size,
                              hipStream_t stream) {
    const float* input   = (const float*)d_in[0];
    const float* hidden0 = (const float*)d_in[1];
    const float* stack   = (const float*)d_in[2];
    const float* W_ih    = (const float*)d_in[3];
    const float* W_hh    = (const float*)d_in[4];
    const float* b_ih    = (const float*)d_in[5];
    const float* b_hh    = (const float*)d_in[6];
    const float* W_y     = (const float*)d_in[7];
    const float* b_y     = (const float*)d_in[8];
    const float* W_n     = (const float*)d_in[9];
    const float* b_n     = (const float*)d_in[10];
    const float* W_a     = (const float*)d_in[11];
    const float* b_a     = (const float*)d_in[12];
    const float* W_sh    = (const float*)d_in[13];
    const float* b_sh    = (const float*)d_in[14];
    float* out = (float*)d_out;
    float* ws  = (float*)d_ws;

    // A: 1024 rows, 4 waves/block -> 256 blocks
    k_pre<<<256, 256, 0, stream>>>(input, hidden0, stack, W_ih, b_ih, W_sh, b_sh, ws);
    // B: 1024 rows
    k_h<<<256, 256, 0, stream>>>(W_hh, b_hh, ws, out);
    // C: 641 rows -> ceil(641/4) = 161 blocks
    k_heads<<<161, 256, 0, stream>>>(W_y, b_y, W_n, b_n, W_a, b_a, ws, out);
    // D: blend, branchless grid-stride
    k_stack<<<2048, 256, 0, stream>>>(stack, ws, out + OUTN + HID);
}